// Round 13
// baseline (666.686 us; speedup 1.0000x reference)
//
#include <hip/hip_runtime.h>

#define TT 1024
#define DD 32
#define HH 64

typedef __fp16 h2v __attribute__((ext_vector_type(2)));
typedef _Float16 f16x8 __attribute__((ext_vector_type(8)));
typedef float f32x4 __attribute__((ext_vector_type(4)));

struct __attribute__((aligned(16))) H4 { h2v p[4]; };

__device__ __forceinline__ h2v pk(float a, float b) {
    return __builtin_amdgcn_cvt_pkrtz(a, b);
}
__device__ __forceinline__ float fsig(float x) {
    float e = __builtin_amdgcn_exp2f(-1.4426950408889634f * x);
    return __builtin_amdgcn_rcpf(1.0f + e);
}
__device__ __forceinline__ float ftanh(float x) {
    float e = __builtin_amdgcn_exp2f(2.885390081777927f * x);
    return 1.0f - 2.0f * __builtin_amdgcn_rcpf(1.0f + e);
}
// LDS-only barrier: orders ds ops, does NOT drain vmcnt -> global prefetches
// (x ring) stay in flight across it. All cross-wave loop traffic is via LDS.
__device__ __forceinline__ void bar_lds() {
    asm volatile("s_waitcnt lgkmcnt(0)\n\ts_barrier" ::: "memory");
}
// select reg r (r = s1*2+s0) of a C-fragment: 3 cndmasks
__device__ __forceinline__ float pick4(f32x4 c, bool s0, bool s1) {
    float lo = s0 ? c[1] : c[0];
    float hi = s0 ? c[3] : c[2];
    return s1 ? hi : lo;
}
__device__ __forceinline__ f16x8 packx(float4 a, float4 b) {
    H4 t;
    t.p[0] = pk(a.x, a.y); t.p[1] = pk(a.z, a.w);
    t.p[2] = pk(b.x, b.y); t.p[3] = pk(b.z, b.w);
    return __builtin_bit_cast(f16x8, t);
}
// A-fragment: 8 consecutive fp32 weights -> packed f16 (lane = A[m=lane&15][k=quad*8+i])
__device__ __forceinline__ f16x8 load_afrag(const float* p) {
    return packx(*(const float4*)p, *(const float4*)(p + 4));
}
#define MFMA16(A, B, C) __builtin_amdgcn_mfma_f32_16x16x32_f16(A, B, C, 0, 0, 0)

// ---------------------------------------------------------------------------
// 64 blocks x 512 threads; block = 4 batch elements.
// Waves 0-3: L1 (j-slice = wave). Waves 4-7: L2 (one step behind).
// LDS per parity: 4 chunks x [batch4][quad4][8 f16]:
//   chunks 0,1 = h1(t-1)   chunks 2,3 = h2(t-2)
// x enters L1 as a REGISTER B-fragment (per-lane direct global load, 3-deep
// prefetch ring) -> no LDS staging, no vmcnt at the barrier, and the x-MFMA
// overlaps the h ds_read latency.
// B cols = 4 batches x 4 reps (col&3 = batch). C layout (m89): col=lane&15,
// row=quad*4+reg -> lane owns unique cell (j=js*16+quad*4+rsel, batch=lane&3).
// MFMA dep chains split 2+1 (L1) / 2+2 (L2); combined after pick4.
// ---------------------------------------------------------------------------
__global__ __launch_bounds__(512) void lstm2_b4v2(
    const float* __restrict__ x,
    const float* __restrict__ w_ih_l0, const float* __restrict__ w_hh_l0,
    const float* __restrict__ b_ih_l0, const float* __restrict__ b_hh_l0,
    const float* __restrict__ w_ih_l1, const float* __restrict__ w_hh_l1,
    const float* __restrict__ b_ih_l1, const float* __restrict__ b_hh_l1,
    const float* __restrict__ w_fc,   const float* __restrict__ b_fc,
    float* __restrict__ out)
{
    const int bbase = blockIdx.x * 4;
    const int tid  = threadIdx.x;
    const int wave = tid >> 6;
    const int lane = tid & 63;
    const bool isL1 = wave < 4;
    const int js   = wave & 3;
    const int quad = lane >> 4;
    const int bb   = lane & 3;
    const int rsel = (lane >> 2) & 3;
    const int jj   = js*16 + quad*4 + rsel;
    const int mrow = lane & 15;

    __shared__ __attribute__((aligned(16))) __fp16 buf[1024];  // [2][4][4][4][8]
    ((int*)buf)[tid] = 0;   // zero both parities (512 dwords)

    // ---- A fragments (weights), biases ----
    f16x8 A[16];
    float bs0, bs1, bs2, bs3;
    if (isL1) {
        #pragma unroll
        for (int q = 0; q < 4; ++q) {
            const int g = q*64 + js*16 + mrow;
            A[q*3 + 0] = load_afrag(w_ih_l0 + (size_t)g*DD + quad*8);
            A[q*3 + 1] = load_afrag(w_hh_l0 + (size_t)g*HH + quad*8);
            A[q*3 + 2] = load_afrag(w_hh_l0 + (size_t)g*HH + 32 + quad*8);
        }
        bs0 = b_ih_l0[0*64 + jj] + b_hh_l0[0*64 + jj];
        bs1 = b_ih_l0[1*64 + jj] + b_hh_l0[1*64 + jj];
        bs2 = b_ih_l0[2*64 + jj] + b_hh_l0[2*64 + jj];
        bs3 = b_ih_l0[3*64 + jj] + b_hh_l0[3*64 + jj];
    } else {
        #pragma unroll
        for (int q = 0; q < 4; ++q) {
            const int g = q*64 + js*16 + mrow;
            A[q*4 + 0] = load_afrag(w_ih_l1 + (size_t)g*HH + quad*8);
            A[q*4 + 1] = load_afrag(w_ih_l1 + (size_t)g*HH + 32 + quad*8);
            A[q*4 + 2] = load_afrag(w_hh_l1 + (size_t)g*HH + quad*8);
            A[q*4 + 3] = load_afrag(w_hh_l1 + (size_t)g*HH + 32 + quad*8);
        }
        bs0 = b_ih_l1[0*64 + jj] + b_hh_l1[0*64 + jj];
        bs1 = b_ih_l1[1*64 + jj] + b_hh_l1[1*64 + jj];
        bs2 = b_ih_l1[2*64 + jj] + b_hh_l1[2*64 + jj];
        bs3 = b_ih_l1[3*64 + jj] + b_hh_l1[3*64 + jj];
    }

    // LDS offsets (f16 units)
    const int roff = (bb*4 + quad)*8;
    const int cw   = (isL1 ? 0 : 2) + (jj >> 5);
    const int woff = ((cw*4 + bb)*4 + ((jj & 31) >> 3))*8 + (jj & 7);

    // x ring (L1 waves): this lane's 8-float slice of x[batch=bb][t][quad*8..+7]
    const float* xg = x + (size_t)(bbase + bb) * (TT*DD) + quad*8;
    float4 r0a, r0b, r1a, r1b, r2a, r2b;
    if (isL1) {
        r0a = *(const float4*)(xg);          r0b = *(const float4*)(xg + 4);
        r1a = *(const float4*)(xg + DD);     r1b = *(const float4*)(xg + DD + 4);
        r2a = *(const float4*)(xg + 2*DD);   r2b = *(const float4*)(xg + 2*DD + 4);
    }

    __syncthreads();

    const bool s0 = (rsel & 1) != 0;
    const bool s1 = (rsel & 2) != 0;
    float cst = 0.0f;
    const f32x4 Z = {0.f, 0.f, 0.f, 0.f};

    for (int t = 0; t <= TT; ++t) {
        const int p = t & 1;
        const __fp16* bc = buf + p*512;
        __fp16* bn = buf + (p ^ 1)*512;
        if (isL1) {
            if (t < TT) {
                f16x8 Bx = packx(r0a, r0b);
                // rotate ring, prefetch x(t+3)
                r0a = r1a; r0b = r1b; r1a = r2a; r1b = r2b;
                const int tl = (t + 3 < TT) ? (t + 3) : (TT - 1);
                r2a = *(const float4*)(xg + (size_t)tl*DD);
                r2b = *(const float4*)(xg + (size_t)tl*DD + 4);

                f16x8 B1 = *(const f16x8*)(bc + 0*128 + roff);
                f16x8 B2 = *(const f16x8*)(bc + 1*128 + roff);

                // x-chains first (register operands -> overlap ds_read latency)
                f32x4 C0 = MFMA16(A[0], Bx, Z);
                f32x4 C1 = MFMA16(A[3], Bx, Z);
                f32x4 C2 = MFMA16(A[6], Bx, Z);
                f32x4 C3 = MFMA16(A[9], Bx, Z);
                C0 = MFMA16(A[1],  B1, C0);
                C1 = MFMA16(A[4],  B1, C1);
                C2 = MFMA16(A[7],  B1, C2);
                C3 = MFMA16(A[10], B1, C3);
                f32x4 D0 = MFMA16(A[2],  B2, Z);
                f32x4 D1 = MFMA16(A[5],  B2, Z);
                f32x4 D2 = MFMA16(A[8],  B2, Z);
                f32x4 D3 = MFMA16(A[11], B2, Z);

                float Si = pick4(C0, s0, s1) + pick4(D0, s0, s1) + bs0;
                float Sf = pick4(C1, s0, s1) + pick4(D1, s0, s1) + bs1;
                float Sg = pick4(C2, s0, s1) + pick4(D2, s0, s1) + bs2;
                float So = pick4(C3, s0, s1) + pick4(D3, s0, s1) + bs3;

                float ii = fsig(Si), ff = fsig(Sf), oo = fsig(So);
                float gg = ftanh(Sg);
                cst = ff * cst + ii * gg;
                float hv = oo * ftanh(cst);
                bn[woff] = (__fp16)hv;
            }
        } else {
            if (t > 0) {
                f16x8 B1 = *(const f16x8*)(bc + 0*128 + roff);
                f16x8 B2 = *(const f16x8*)(bc + 1*128 + roff);
                f16x8 B3 = *(const f16x8*)(bc + 2*128 + roff);
                f16x8 B4 = *(const f16x8*)(bc + 3*128 + roff);

                f32x4 C0 = MFMA16(A[0],  B1, Z); C0 = MFMA16(A[1],  B2, C0);
                f32x4 C1 = MFMA16(A[4],  B1, Z); C1 = MFMA16(A[5],  B2, C1);
                f32x4 C2 = MFMA16(A[8],  B1, Z); C2 = MFMA16(A[9],  B2, C2);
                f32x4 C3 = MFMA16(A[12], B1, Z); C3 = MFMA16(A[13], B2, C3);
                f32x4 D0 = MFMA16(A[2],  B3, Z); D0 = MFMA16(A[3],  B4, D0);
                f32x4 D1 = MFMA16(A[6],  B3, Z); D1 = MFMA16(A[7],  B4, D1);
                f32x4 D2 = MFMA16(A[10], B3, Z); D2 = MFMA16(A[11], B4, D2);
                f32x4 D3 = MFMA16(A[14], B3, Z); D3 = MFMA16(A[15], B4, D3);

                float Si = pick4(C0, s0, s1) + pick4(D0, s0, s1) + bs0;
                float Sf = pick4(C1, s0, s1) + pick4(D1, s0, s1) + bs1;
                float Sg = pick4(C2, s0, s1) + pick4(D2, s0, s1) + bs2;
                float So = pick4(C3, s0, s1) + pick4(D3, s0, s1) + bs3;

                float ii = fsig(Si), ff = fsig(Sf), oo = fsig(So);
                float gg = ftanh(Sg);
                cst = ff * cst + ii * gg;
                float hv = oo * ftanh(cst);
                bn[woff] = (__fp16)hv;
            }
        }
        bar_lds();
    }

    // h2(TT-1) sits in parity 1, chunks 2,3. FC + sigmoid (wave 0).
    if (wave == 0) {
        const int jg = lane >> 2;   // 0..15
        float s = 0.f;
        #pragma unroll
        for (int u2 = 0; u2 < 4; ++u2) {
            const int j = jg*4 + u2;
            float hval = (float)buf[512 + (((2 + (j >> 5))*4 + bb)*4 + ((j & 31) >> 3))*8 + (j & 7)];
            s += hval * w_fc[j];
        }
        s += __shfl_xor(s, 4);
        s += __shfl_xor(s, 8);
        s += __shfl_xor(s, 16);
        s += __shfl_xor(s, 32);
        if (lane < 4) out[bbase + lane] = fsig(s + b_fc[0]);
    }
}

extern "C" void kernel_launch(void* const* d_in, const int* in_sizes, int n_in,
                              void* d_out, int out_size, void* d_ws, size_t ws_size,
                              hipStream_t stream) {
    lstm2_b4v2<<<dim3(64), dim3(512), 0, stream>>>(
        (const float*)d_in[0],
        (const float*)d_in[1], (const float*)d_in[2],
        (const float*)d_in[3], (const float*)d_in[4],
        (const float*)d_in[5], (const float*)d_in[6],
        (const float*)d_in[7], (const float*)d_in[8],
        (const float*)d_in[9], (const float*)d_in[10],
        (float*)d_out);
}

// Round 14
// 551.292 us; speedup vs baseline: 1.2093x; 1.2093x over previous
//
#include <hip/hip_runtime.h>

#define TT 1024
#define DD 32
#define HH 64

typedef __fp16 h2v __attribute__((ext_vector_type(2)));
typedef _Float16 f16x8 __attribute__((ext_vector_type(8)));
typedef float f32x4 __attribute__((ext_vector_type(4)));

struct __attribute__((aligned(16))) H4 { h2v p[4]; };

__device__ __forceinline__ h2v pk(float a, float b) {
    return __builtin_amdgcn_cvt_pkrtz(a, b);
}
__device__ __forceinline__ float fsig(float x) {
    float e = __builtin_amdgcn_exp2f(-1.4426950408889634f * x);
    return __builtin_amdgcn_rcpf(1.0f + e);
}
__device__ __forceinline__ float ftanh(float x) {
    float e = __builtin_amdgcn_exp2f(2.885390081777927f * x);
    return 1.0f - 2.0f * __builtin_amdgcn_rcpf(1.0f + e);
}
// LDS-only barrier: orders ds ops but does NOT drain vmcnt, so wave 7's x
// prefetch loads stay in flight across the step boundary. All cross-wave
// loop traffic is via LDS (h1/h2/x-staging), which lgkmcnt(0)+s_barrier orders.
__device__ __forceinline__ void bar_lds() {
    asm volatile("s_waitcnt lgkmcnt(0)\n\ts_barrier" ::: "memory");
}
// select reg r (r = s1*2+s0) of a C-fragment: 3 cndmasks
__device__ __forceinline__ float pick4(f32x4 c, bool s0, bool s1) {
    float lo = s0 ? c[1] : c[0];
    float hi = s0 ? c[3] : c[2];
    return s1 ? hi : lo;
}
// A-fragment: 8 consecutive fp32 weights -> packed f16 (lane = A[m=lane&15][k=quad*8+i])
__device__ __forceinline__ f16x8 load_afrag(const float* p) {
    float4 f0 = *(const float4*)p;
    float4 f1 = *(const float4*)(p + 4);
    H4 t;
    t.p[0] = pk(f0.x, f0.y); t.p[1] = pk(f0.z, f0.w);
    t.p[2] = pk(f1.x, f1.y); t.p[3] = pk(f1.z, f1.w);
    return __builtin_bit_cast(f16x8, t);
}
#define MFMA16(A, B, C) __builtin_amdgcn_mfma_f32_16x16x32_f16(A, B, C, 0, 0, 0)

// ---------------------------------------------------------------------------
// R12 structure (best verified: 490 us main), single change: in-loop barrier
// is lgkm-only (bar_lds) so wave 7's x prefetch never drains at the barrier.
//
// 64 blocks x 512 threads; block = 4 batch elements.
// Waves 0-3: L1 (j-slice = wave). Waves 4-7: L2 (one step behind); wave 7
// stages x(t+1) into LDS (fp32->f16) with a 2-deep register prefetch ring.
// LDS per parity: 5 chunks x [batch4][quad4][8 f16]:
//   chunk 0 = x(t), chunks 1,2 = h1(t-1), chunks 3,4 = h2(t-2)
// B cols = 4 batches x 4 reps (col&3 = batch). C layout (m89): col=lane&15,
// row=quad*4+reg -> lane owns unique cell (j=js*16+quad*4+rsel, batch=lane&3).
// ---------------------------------------------------------------------------
__global__ __launch_bounds__(512) void lstm2_b4v3(
    const float* __restrict__ x,
    const float* __restrict__ w_ih_l0, const float* __restrict__ w_hh_l0,
    const float* __restrict__ b_ih_l0, const float* __restrict__ b_hh_l0,
    const float* __restrict__ w_ih_l1, const float* __restrict__ w_hh_l1,
    const float* __restrict__ b_ih_l1, const float* __restrict__ b_hh_l1,
    const float* __restrict__ w_fc,   const float* __restrict__ b_fc,
    float* __restrict__ out)
{
    const int bbase = blockIdx.x * 4;
    const int tid  = threadIdx.x;
    const int wave = tid >> 6;
    const int lane = tid & 63;
    const bool isL1 = wave < 4;
    const int js   = wave & 3;
    const int quad = lane >> 4;
    const int bb   = lane & 3;
    const int rsel = (lane >> 2) & 3;
    const int jj   = js*16 + quad*4 + rsel;
    const int mrow = lane & 15;

    __shared__ __attribute__((aligned(16))) __fp16 buf[1280];  // [2][5][4][4][8]

    {
        int* bi = (int*)buf;
        bi[tid] = 0;
        if (tid < 128) bi[512 + tid] = 0;
    }

    // ---- A fragments (weights), biases ----
    f16x8 A[16];
    float bs0, bs1, bs2, bs3;
    if (isL1) {
        #pragma unroll
        for (int q = 0; q < 4; ++q) {
            const int g = q*64 + js*16 + mrow;
            A[q*3 + 0] = load_afrag(w_ih_l0 + (size_t)g*DD + quad*8);
            A[q*3 + 1] = load_afrag(w_hh_l0 + (size_t)g*HH + quad*8);
            A[q*3 + 2] = load_afrag(w_hh_l0 + (size_t)g*HH + 32 + quad*8);
        }
        bs0 = b_ih_l0[0*64 + jj] + b_hh_l0[0*64 + jj];
        bs1 = b_ih_l0[1*64 + jj] + b_hh_l0[1*64 + jj];
        bs2 = b_ih_l0[2*64 + jj] + b_hh_l0[2*64 + jj];
        bs3 = b_ih_l0[3*64 + jj] + b_hh_l0[3*64 + jj];
    } else {
        #pragma unroll
        for (int q = 0; q < 4; ++q) {
            const int g = q*64 + js*16 + mrow;
            A[q*4 + 0] = load_afrag(w_ih_l1 + (size_t)g*HH + quad*8);
            A[q*4 + 1] = load_afrag(w_ih_l1 + (size_t)g*HH + 32 + quad*8);
            A[q*4 + 2] = load_afrag(w_hh_l1 + (size_t)g*HH + quad*8);
            A[q*4 + 3] = load_afrag(w_hh_l1 + (size_t)g*HH + 32 + quad*8);
        }
        bs0 = b_ih_l1[0*64 + jj] + b_hh_l1[0*64 + jj];
        bs1 = b_ih_l1[1*64 + jj] + b_hh_l1[1*64 + jj];
        bs2 = b_ih_l1[2*64 + jj] + b_hh_l1[2*64 + jj];
        bs3 = b_ih_l1[3*64 + jj] + b_hh_l1[3*64 + jj];
    }

    // per-lane LDS offsets (f16 units)
    const int roff = (bb*4 + quad)*8;
    const int cw   = (isL1 ? 1 : 3) + (jj >> 5);
    const int woff = ((cw*4 + bb)*4 + ((jj & 31) >> 3))*8 + (jj & 7);

    // x stager (wave 7): lane -> (batch = lane>>4, k-pair = lane&15)
    const float* xg = x + (size_t)(bbase + (lane >> 4)) * (TT*DD) + (lane & 15)*2;
    const int sdw = ((lane >> 4)*4 + ((lane & 15) >> 2))*4 + ((lane & 15) & 3);
    float2 xv1 = {0.f, 0.f}, xv2 = {0.f, 0.f};

    __syncthreads();   // zero-init visible before x(0) staging
    if (wave == 7) {
        float2 v0 = *(const float2*)xg;                       // x(0)
        ((int*)buf)[sdw] = __builtin_bit_cast(int, pk(v0.x, v0.y));
        xv1 = *(const float2*)(xg + DD);                      // x(1)
        xv2 = *(const float2*)(xg + 2*DD);                    // x(2)
    }
    __syncthreads();

    const bool s0 = (rsel & 1) != 0;
    const bool s1 = (rsel & 2) != 0;
    float cst = 0.0f;

    for (int t = 0; t <= TT; ++t) {
        const int p = t & 1;
        const __fp16* bc = buf + p*640;
        __fp16* bn = buf + (p ^ 1)*640;
        if (isL1) {
            if (t < TT) {
                f16x8 B0 = *(const f16x8*)(bc + 0*128 + roff);
                f16x8 B1 = *(const f16x8*)(bc + 1*128 + roff);
                f16x8 B2 = *(const f16x8*)(bc + 2*128 + roff);

                f32x4 Z = {0.f, 0.f, 0.f, 0.f};
                f32x4 C0 = Z, C1 = Z, C2 = Z, C3 = Z;
                C0 = MFMA16(A[0], B0, C0); C0 = MFMA16(A[1],  B1, C0); C0 = MFMA16(A[2],  B2, C0);
                C1 = MFMA16(A[3], B0, C1); C1 = MFMA16(A[4],  B1, C1); C1 = MFMA16(A[5],  B2, C1);
                C2 = MFMA16(A[6], B0, C2); C2 = MFMA16(A[7],  B1, C2); C2 = MFMA16(A[8],  B2, C2);
                C3 = MFMA16(A[9], B0, C3); C3 = MFMA16(A[10], B1, C3); C3 = MFMA16(A[11], B2, C3);

                float Si = pick4(C0, s0, s1) + bs0;
                float Sf = pick4(C1, s0, s1) + bs1;
                float Sg = pick4(C2, s0, s1) + bs2;
                float So = pick4(C3, s0, s1) + bs3;

                float ii = fsig(Si), ff = fsig(Sf), oo = fsig(So);
                float gg = ftanh(Sg);
                cst = ff * cst + ii * gg;
                float hv = oo * ftanh(cst);
                bn[woff] = (__fp16)hv;
            }
        } else {
            if (wave == 7 && t < TT) {   // stage x(t+1) into next buffer
                ((int*)bn)[sdw] = __builtin_bit_cast(int, pk(xv1.x, xv1.y));
                xv1 = xv2;
                const int tl = (t + 3 < TT) ? (t + 3) : (TT - 1);
                xv2 = *(const float2*)(xg + (size_t)tl*DD);
            }
            if (t > 0) {
                f16x8 B1 = *(const f16x8*)(bc + 1*128 + roff);
                f16x8 B2 = *(const f16x8*)(bc + 2*128 + roff);
                f16x8 B3 = *(const f16x8*)(bc + 3*128 + roff);
                f16x8 B4 = *(const f16x8*)(bc + 4*128 + roff);

                f32x4 Z = {0.f, 0.f, 0.f, 0.f};
                f32x4 C0 = Z, C1 = Z, C2 = Z, C3 = Z;
                C0 = MFMA16(A[0],  B1, C0); C0 = MFMA16(A[1],  B2, C0);
                C0 = MFMA16(A[2],  B3, C0); C0 = MFMA16(A[3],  B4, C0);
                C1 = MFMA16(A[4],  B1, C1); C1 = MFMA16(A[5],  B2, C1);
                C1 = MFMA16(A[6],  B3, C1); C1 = MFMA16(A[7],  B4, C1);
                C2 = MFMA16(A[8],  B1, C2); C2 = MFMA16(A[9],  B2, C2);
                C2 = MFMA16(A[10], B3, C2); C2 = MFMA16(A[11], B4, C2);
                C3 = MFMA16(A[12], B1, C3); C3 = MFMA16(A[13], B2, C3);
                C3 = MFMA16(A[14], B3, C3); C3 = MFMA16(A[15], B4, C3);

                float Si = pick4(C0, s0, s1) + bs0;
                float Sf = pick4(C1, s0, s1) + bs1;
                float Sg = pick4(C2, s0, s1) + bs2;
                float So = pick4(C3, s0, s1) + bs3;

                float ii = fsig(Si), ff = fsig(Sf), oo = fsig(So);
                float gg = ftanh(Sg);
                cst = ff * cst + ii * gg;
                float hv = oo * ftanh(cst);
                bn[woff] = (__fp16)hv;
            }
        }
        bar_lds();
    }

    // h2(TT-1) sits in buf parity 1, chunks 3,4. FC + sigmoid (wave 0).
    if (wave == 0) {
        const int jg = lane >> 2;   // 0..15
        float s = 0.f;
        #pragma unroll
        for (int u2 = 0; u2 < 4; ++u2) {
            const int j = jg*4 + u2;
            float hval = (float)buf[640 + (((3 + (j >> 5))*4 + bb)*4 + ((j & 31) >> 3))*8 + (j & 7)];
            s += hval * w_fc[j];
        }
        s += __shfl_xor(s, 4);
        s += __shfl_xor(s, 8);
        s += __shfl_xor(s, 16);
        s += __shfl_xor(s, 32);
        if (lane < 4) out[bbase + lane] = fsig(s + b_fc[0]);
    }
}

extern "C" void kernel_launch(void* const* d_in, const int* in_sizes, int n_in,
                              void* d_out, int out_size, void* d_ws, size_t ws_size,
                              hipStream_t stream) {
    lstm2_b4v3<<<dim3(64), dim3(512), 0, stream>>>(
        (const float*)d_in[0],
        (const float*)d_in[1], (const float*)d_in[2],
        (const float*)d_in[3], (const float*)d_in[4],
        (const float*)d_in[5], (const float*)d_in[6],
        (const float*)d_in[7], (const float*)d_in[8],
        (const float*)d_in[9], (const float*)d_in[10],
        (float*)d_out);
}